// Round 7
// baseline (155.524 us; speedup 1.0000x reference)
//
#include <hip/hip_runtime.h>
#include <stdint.h>

// ---------------------------------------------------------------------------
// Fused MHA block: qkv proj -> flash attention -> out proj.
// Inputs fp32, output fp32; bf16 MFMA compute, fp32 accum.
// B=4 N=2048 C=512 H=8 D=64 fixed.
// R24: attn_fused = R22 decomposition + half-tile (mt) granularity T15
// pipeline. Per tile t: QK(t,mt1)->sB; softmax(sA)||PV(mt0); QK(t+1,mt0)
// ->sA; softmax(sB)||PV(mt1); drain+barrier. Every softmax VALU block has
// an independent 8-MFMA QK cluster in flight (MFMA ~33K cyc/SIMD and
// softmax VALU ~33K cyc/SIMD ran SERIALLY in R14..R22 via the QK->exp->PV
// chain: 29%+31% busy, 40% stall). Half-tile S-state = 64 VGPR (sA,sB
// pairs), total ~230 < 256 cap. R23's fatal __launch_bounds__(512,2)
// (128-VGPR cap vs ~280 live -> mega-spill/timeout) fixed: bounds(512).
// ---------------------------------------------------------------------------

typedef short bf16x8 __attribute__((ext_vector_type(8)));   // 8 bf16 = 4 VGPRs
typedef float f32x2  __attribute__((ext_vector_type(2)));
typedef float f32x4  __attribute__((ext_vector_type(4)));
typedef float f32x16 __attribute__((ext_vector_type(16)));
typedef unsigned int u32x4 __attribute__((ext_vector_type(4)));

__device__ __forceinline__ unsigned short f2bf(float f) {
    unsigned int u = __builtin_bit_cast(unsigned int, f);
    u += 0x7fffu + ((u >> 16) & 1u);
    return (unsigned short)(u >> 16);
}
__device__ __forceinline__ unsigned int pk2(float a, float b) {
    return (unsigned int)f2bf(a) | ((unsigned int)f2bf(b) << 16);
}
__device__ __forceinline__ float fexp2(float x) {
    return __builtin_amdgcn_exp2f(x);    // bare v_exp_f32
}
__device__ __forceinline__ bf16x8 ld8_f32(const float* __restrict__ p) {
    float4 f0 = *(const float4*)p;
    float4 f1 = *(const float4*)(p + 4);
    u32x4 u = {pk2(f0.x, f0.y), pk2(f0.z, f0.w), pk2(f1.x, f1.y), pk2(f1.z, f1.w)};
    return __builtin_bit_cast(bf16x8, u);
}
__device__ __forceinline__ void async16(const void* g, void* l) {
    __builtin_amdgcn_global_load_lds(
        (const __attribute__((address_space(1))) unsigned int*)g,
        (__attribute__((address_space(3))) unsigned int*)l,
        16, 0, 0);
}

#define MFMA16(a, b, c) __builtin_amdgcn_mfma_f32_16x16x32_bf16((a), (b), (c), 0, 0, 0)
#define MFMA32(a, b, c) __builtin_amdgcn_mfma_f32_32x32x16_bf16((a), (b), (c), 0, 0, 0)

// ---------------------------------------------------------------------------
// fp32 -> bf16 bulk convert: x, qkv_w, proj_w in one pass.
// ---------------------------------------------------------------------------
__global__ void cvt_bf16(const float* __restrict__ x,
                         const float* __restrict__ w,
                         const float* __restrict__ w2,
                         unsigned short* __restrict__ xb,
                         unsigned short* __restrict__ wb,
                         unsigned short* __restrict__ wb2)
{
    const int G = 524288 + 98304 + 32768;
    for (int idx = blockIdx.x * 256 + threadIdx.x; idx < G; idx += gridDim.x * 256) {
        if (idx < 524288)
            *(bf16x8*)(xb + (size_t)idx * 8) = ld8_f32(x + (size_t)idx * 8);
        else if (idx < 524288 + 98304) {
            int j = idx - 524288;
            *(bf16x8*)(wb + (size_t)j * 8) = ld8_f32(w + (size_t)j * 8);
        } else {
            int j = idx - 524288 - 98304;
            *(bf16x8*)(wb2 + (size_t)j * 8) = ld8_f32(w2 + (size_t)j * 8);
        }
    }
}

// ---------------------------------------------------------------------------
// QKV GEMM: 128x128 tile / 4 waves; BK=32; dual DMA staging; 4 blocks/CU.
// XCD remap: XCD k owns A-rows [8k,8k+8) x all 12 col-tiles.
// ---------------------------------------------------------------------------
__global__ __launch_bounds__(256, 4)
void gemm_qkv(const unsigned short* __restrict__ A,
              const unsigned short* __restrict__ B,
              const float* __restrict__ bias,
              unsigned short* __restrict__ out0,
              unsigned short* __restrict__ out1,
              unsigned short* __restrict__ out2,
              int K)
{
    __shared__ unsigned short sA[128 * 32];
    __shared__ unsigned short sB[128 * 32];

    const int tid  = threadIdx.x;
    const int wave = tid >> 6, lane = tid & 63;
    const int l = lane & 15, q16 = lane >> 4;
    const int wm = wave >> 1, wn = wave & 1;
    const int bid = blockIdx.x;                  // 0..767
    const int slot = bid >> 3;                   // 0..95
    const int m0 = ((bid & 7) * 8 + slot / 12) * 128;
    const int n0 = (slot % 12) * 128;

    f32x4 acc[4][4];
#pragma unroll
    for (int i = 0; i < 4; ++i)
#pragma unroll
        for (int j = 0; j < 4; ++j)
            acc[i][j] = (f32x4){0.f, 0.f, 0.f, 0.f};

    for (int k0 = 0; k0 < K; k0 += 32) {
#pragma unroll
        for (int call = 0; call < 2; ++call) {
            int L = call * 256 + tid;
            int r = L >> 2, c = L & 3;
            async16(A + (size_t)(m0 + r) * K + k0 + c * 8, sA + L * 8);
            async16(B + (size_t)(n0 + r) * K + k0 + c * 8, sB + L * 8);
        }
        __syncthreads();

        bf16x8 af[4], bfr[4];
#pragma unroll
        for (int i = 0; i < 4; ++i)
            af[i] = *(const bf16x8*)(sA + ((wm * 64 + i * 16 + l) * 4 + q16) * 8);
#pragma unroll
        for (int j = 0; j < 4; ++j)
            bfr[j] = *(const bf16x8*)(sB + ((wn * 64 + j * 16 + l) * 4 + q16) * 8);
#pragma unroll
        for (int i = 0; i < 4; ++i)
#pragma unroll
            for (int j = 0; j < 4; ++j)
                acc[i][j] = MFMA16(af[i], bfr[j], acc[i][j]);
        __syncthreads();
    }

    const float lscale = 0.18033688f;  // D^-0.5 * log2(e), folded into q
#pragma unroll
    for (int i = 0; i < 4; ++i) {
#pragma unroll
        for (int j = 0; j < 4; ++j) {
            int col = n0 + wn * 64 + j * 16 + l;
            float bv = bias[col];
#pragma unroll
            for (int r = 0; r < 4; ++r) {
                int row = m0 + wm * 64 + i * 16 + q16 * 4 + r;
                float val = acc[i][j][r] + bv;
                int which = col >> 9;            // 0:q 1:k 2:v
                int h = (col >> 6) & 7, d = col & 63;
                int b = row >> 11, n = row & 2047;
                if (which == 0)
                    out0[(size_t)(((b * 8 + h) * 2048) + n) * 64 + d] = f2bf(val * lscale);
                else if (which == 1)
                    out1[(size_t)(((b * 8 + h) * 2048) + n) * 64 + d] = f2bf(val);
                else {
                    // V^T with pi(n): swap bits 2<->3 of n (within 32-blocks)
                    int np = (n & ~12) | ((n & 8) >> 1) | ((n & 4) << 1);
                    out2[(size_t)(((b * 8 + h) * 64) + d) * 2048 + np] = f2bf(val);
                }
            }
        }
    }
}

// ---------------------------------------------------------------------------
// Output GEMM: 64x128 tile / 4 waves; BK=32; 4 blocks/CU. fp32 out + bias.
// XCD remap: XCD k owns rows [16k,16k+16) x 4 col-tiles.
// ---------------------------------------------------------------------------
__global__ __launch_bounds__(256, 4)
void gemm_out(const unsigned short* __restrict__ A,
              const unsigned short* __restrict__ B,
              const float* __restrict__ bias,
              float* __restrict__ outf,
              int K, int N)
{
    __shared__ unsigned short sA[64 * 32];
    __shared__ unsigned short sB[128 * 32];

    const int tid  = threadIdx.x;
    const int wave = tid >> 6, lane = tid & 63;
    const int l = lane & 15, q16 = lane >> 4;
    const int wm = wave >> 1, wn = wave & 1;
    const int bid = blockIdx.x;                  // 0..511
    const int slot = bid >> 3;                   // 0..63
    const int m0 = ((bid & 7) * 16 + (slot >> 2)) * 64;
    const int n0 = (slot & 3) * 128;

    f32x4 acc[2][4];
#pragma unroll
    for (int i = 0; i < 2; ++i)
#pragma unroll
        for (int j = 0; j < 4; ++j)
            acc[i][j] = (f32x4){0.f, 0.f, 0.f, 0.f};

    for (int k0 = 0; k0 < K; k0 += 32) {
        {
            int r = tid >> 2, c = tid & 3;       // A: 256 slots
            async16(A + (size_t)(m0 + r) * K + k0 + c * 8, sA + tid * 8);
        }
#pragma unroll
        for (int call = 0; call < 2; ++call) {   // B: 512 slots
            int L = call * 256 + tid;
            int r = L >> 2, c = L & 3;
            async16(B + (size_t)(n0 + r) * K + k0 + c * 8, sB + L * 8);
        }
        __syncthreads();

        bf16x8 af[2], bfr[4];
#pragma unroll
        for (int i = 0; i < 2; ++i)
            af[i] = *(const bf16x8*)(sA + ((wm * 32 + i * 16 + l) * 4 + q16) * 8);
#pragma unroll
        for (int j = 0; j < 4; ++j)
            bfr[j] = *(const bf16x8*)(sB + ((wn * 64 + j * 16 + l) * 4 + q16) * 8);
#pragma unroll
        for (int i = 0; i < 2; ++i)
#pragma unroll
            for (int j = 0; j < 4; ++j)
                acc[i][j] = MFMA16(af[i], bfr[j], acc[i][j]);
        __syncthreads();
    }

#pragma unroll
    for (int i = 0; i < 2; ++i) {
#pragma unroll
        for (int j = 0; j < 4; ++j) {
            int col = n0 + wn * 64 + j * 16 + l;
            float bv = bias[col];
#pragma unroll
            for (int r = 0; r < 4; ++r) {
                int row = m0 + wm * 32 + i * 16 + q16 * 4 + r;
                outf[(size_t)row * N + col] = acc[i][j][r] + bv;
            }
        }
    }
}

// ---------------------------------------------------------------------------
// Flash attention R24: 512 threads / 8 waves / 1 block per CU.
// Wave (qq,kh): q-rows qq*64..+63 (qt 0,1) vs kv-half kh*64..+63.
// Half-tile pipeline: subtile s=2t+mt; QK(s+1) always in flight while
// softmax(s) runs on VALU, then PV(s). sA/sB = S(s) static double buffer
// (2 qt x 16 regs each). Triple-buffered LDS, prefetch t+2 at top of iter,
// drained at end-of-iter barrier. kh-partials merged via LDS epilogue.
// ---------------------------------------------------------------------------
__global__ __launch_bounds__(512)
void attn_fused(const unsigned short* __restrict__ Q,
                const unsigned short* __restrict__ Km,
                const unsigned short* __restrict__ Vt,
                unsigned short* __restrict__ O)
{
    __shared__ unsigned short sAll[49152];       // 96 KB: K[3][8192] | V[3][8192]

    const int tid  = threadIdx.x;
    const int wave = tid >> 6, lane = tid & 63;
    const int l31 = lane & 31, h = lane >> 5;
    const int swz = l31 & 7;
    const int qq = wave >> 1, kh = wave & 1;     // qq 0..3, kh 0..1
    const int bid = blockIdx.x;                  // 0..255
    const int slot = bid >> 3;                   // 0..31
    const int bh = (bid & 7) * 4 + (slot >> 3);  // 4 heads per XCD
    const int qc = slot & 7;                     // q-chunk of 256 rows
    const int q0 = qc * 256 + qq * 64;           // this wave: q0..q0+63

    const unsigned short* Kp = Km + (size_t)bh * 2048 * 64;
    const unsigned short* Vp = Vt + (size_t)bh * 64 * 2048;
    unsigned short* sKf = sAll;                  // 3 x 8192-elem K buffers
    unsigned short* sVf = sAll + 24576;          // 3 x 8192-elem V buffers

    // K fragment addrs: row = kh*64 + mt*32 + l31 (row&7 == swz),
    // chunk = (ks*2+h)^swz. mt*2048 added at use.
    int ka[4], va[2][2];
#pragma unroll
    for (int ks = 0; ks < 4; ++ks)
        ka[ks] = (kh * 64 + l31) * 64 + ((ks * 2 + h) ^ swz) * 8;
    // V^T fragment addrs: row = d = l31 (+dt*32 via +4096), kv chunk
    // (mt*4+ks2*2+h)^swz within kh's 64-col half (+kh*64 raw offset).
#pragma unroll
    for (int m1 = 0; m1 < 2; ++m1)
#pragma unroll
        for (int ks2 = 0; ks2 < 2; ++ks2)
            va[m1][ks2] = l31 * 128 + ((m1 * 4 + ks2 * 2 + h) ^ swz) * 8 + kh * 64;

    // staging: 1024 slots of 8 elems, 512 threads -> 2 K slots + 2 V slots
    int ksrc[2], vsrc[2], dsl[2];
#pragma unroll
    for (int c = 0; c < 2; ++c) {
        int s = c * 512 + tid;
        int rk = s >> 3;
        ksrc[c] = rk * 64 + ((s & 7) ^ (rk & 7)) * 8;
        int rv = s >> 4;
        vsrc[c] = rv * 2048 + ((s & 15) ^ (rv & 7)) * 8;
        dsl[c] = s * 8;
    }

    bf16x8 qf[2][4];
#pragma unroll
    for (int qt = 0; qt < 2; ++qt)
#pragma unroll
        for (int ks = 0; ks < 4; ++ks)
            qf[qt][ks] = *(const bf16x8*)(Q + (size_t)(bh * 2048 + q0 + qt * 32 + l31) * 64
                                          + ks * 16 + h * 8);

    f32x16 oacc[2][2];
#pragma unroll
    for (int qt = 0; qt < 2; ++qt)
#pragma unroll
        for (int dt = 0; dt < 2; ++dt)
#pragma unroll
            for (int e = 0; e < 16; ++e) oacc[qt][dt][e] = 0.f;
    f32x16 Zv;
#pragma unroll
    for (int e = 0; e < 16; ++e) Zv[e] = 0.f;
    f32x2 l2[2];
    l2[0] = (f32x2){0.f, 0.f};
    l2[1] = (f32x2){0.f, 0.f};

    f32x16 sA0, sA1, sB0, sB1;                   // S(subtile) static dbuf

    // softmax of one 32-kv subtile (both qt) + its PV MFMAs.
    auto softmax_pv = [&](const f32x16& s0, const f32x16& s1, int mt,
                          const unsigned short* sVc) {
        unsigned int pk0[4][2], pk1[4][2];
#pragma unroll
        for (int g = 0; g < 4; ++g) {
            float a0 = fexp2(s0[4 * g + 0]);
            float a1 = fexp2(s0[4 * g + 1]);
            float a2 = fexp2(s0[4 * g + 2]);
            float a3 = fexp2(s0[4 * g + 3]);
            l2[0] += (f32x2){a0, a1};
            l2[0] += (f32x2){a2, a3};
            pk0[g][0] = __builtin_amdgcn_perm(
                __builtin_bit_cast(unsigned int, a1),
                __builtin_bit_cast(unsigned int, a0), 0x07060302u);
            pk0[g][1] = __builtin_amdgcn_perm(
                __builtin_bit_cast(unsigned int, a3),
                __builtin_bit_cast(unsigned int, a2), 0x07060302u);
            float b0 = fexp2(s1[4 * g + 0]);
            float b1 = fexp2(s1[4 * g + 1]);
            float b2 = fexp2(s1[4 * g + 2]);
            float b3 = fexp2(s1[4 * g + 3]);
            l2[1] += (f32x2){b0, b1};
            l2[1] += (f32x2){b2, b3};
            pk1[g][0] = __builtin_amdgcn_perm(
                __builtin_bit_cast(unsigned int, b1),
                __builtin_bit_cast(unsigned int, b0), 0x07060302u);
            pk1[g][1] = __builtin_amdgcn_perm(
                __builtin_bit_cast(unsigned int, b3),
                __builtin_bit_cast(unsigned int, b2), 0x07060302u);
        }
#pragma unroll
        for (int ks2 = 0; ks2 < 2; ++ks2) {
            u32x4 bu0, bu1;
            bu0[0] = pk0[2 * ks2][0];
            bu0[1] = pk0[2 * ks2][1];
            bu0[2] = pk0[2 * ks2 + 1][0];
            bu0[3] = pk0[2 * ks2 + 1][1];
            bu1[0] = pk1[2 * ks2][0];
            bu1[1] = pk1[2 * ks2][1];
            bu1[2] = pk1[2 * ks2 + 1][0];
            bu1[3] = pk1[2 * ks2 + 1][1];
            bf16x8 bf0 = __builtin_bit_cast(bf16x8, bu0);
            bf16x8 bf1 = __builtin_bit_cast(bf16x8, bu1);
#pragma unroll
            for (int dt = 0; dt < 2; ++dt) {
                bf16x8 vf = *(const bf16x8*)(sVc + va[mt][ks2] + dt * 4096);
                __builtin_amdgcn_s_setprio(1);
                oacc[0][dt] = MFMA32(vf, bf0, oacc[0][dt]);
                oacc[1][dt] = MFMA32(vf, bf1, oacc[1][dt]);
                __builtin_amdgcn_s_setprio(0);
            }
        }
    };

    // prologue: stage tiles 0 and 1; full drain; publish; QK(s=0)->sA.
#pragma unroll
    for (int c = 0; c < 2; ++c) {
        async16(Kp + ksrc[c], (void*)(sKf + dsl[c]));
        async16(Vp + vsrc[c], (void*)(sVf + dsl[c]));
    }
#pragma unroll
    for (int c = 0; c < 2; ++c) {
        async16(Kp + (size_t)128 * 64 + ksrc[c], (void*)(sKf + 8192 + dsl[c]));
        async16(Vp + (size_t)128 + vsrc[c], (void*)(sVf + 8192 + dsl[c]));
    }
    asm volatile("s_waitcnt vmcnt(0)" ::: "memory");
    __builtin_amdgcn_s_barrier();
    __builtin_amdgcn_sched_barrier(0);
    {
        bf16x8 kf = *(const bf16x8*)(sKf + ka[0]);
        sA0 = MFMA32(kf, qf[0][0], Zv);
        sA1 = MFMA32(kf, qf[1][0], Zv);
#pragma unroll
        for (int ks = 1; ks < 4; ++ks) {
            kf = *(const bf16x8*)(sKf + ka[ks]);
            sA0 = MFMA32(kf, qf[0][ks], sA0);
            sA1 = MFMA32(kf, qf[1][ks], sA1);
        }
    }

    int off0 = 0, off1 = 8192, off2 = 16384;     // cur, +1, +2 buffer offsets

    for (int t = 0; t < 16; ++t) {
        const unsigned short* sKc = sKf + off0;
        const unsigned short* sVc = sVf + off0;

        // half 1: prefetch t+2; QK(t,mt1)->sB; softmax(sA) overlaps it; PV(mt0).
        if (t < 14) {
            size_t kv = (size_t)(t + 2) * 128;
#pragma unroll
            for (int c = 0; c < 2; ++c) {
                async16(Kp + kv * 64 + ksrc[c], (void*)(sKf + off2 + dsl[c]));
                async16(Vp + kv + vsrc[c], (void*)(sVf + off2 + dsl[c]));
            }
        }
        {
            bf16x8 kf = *(const bf16x8*)(sKc + ka[0] + 2048);
            __builtin_amdgcn_s_setprio(1);
            sB0 = MFMA32(kf, qf[0][0], Zv);
            sB1 = MFMA32(kf, qf[1][0], Zv);
            __builtin_amdgcn_s_setprio(0);
#pragma unroll
            for (int ks = 1; ks < 4; ++ks) {
                kf = *(const bf16x8*)(sKc + ka[ks] + 2048);
                __builtin_amdgcn_s_setprio(1);
                sB0 = MFMA32(kf, qf[0][ks], sB0);
                sB1 = MFMA32(kf, qf[1][ks], sB1);
                __builtin_amdgcn_s_setprio(0);
            }
        }
        softmax_pv(sA0, sA1, 0, sVc);

        // half 2: QK(t+1,mt0)->sA; softmax(sB) overlaps it; PV(mt1).
        if (t < 15) {
            const unsigned short* sKn = sKf + off1;
            bf16x8 kf = *(const bf16x8*)(sKn + ka[0]);
            __builtin_amdgcn_s_setprio(1);
            sA0 = MFMA32(kf, qf[0][0], Zv);
            sA1 = MFMA32(kf, qf[1][0], Zv);
            __builtin_amdgcn_s_setprio(0);
#pragma unroll
            for (int ks = 1; ks < 4; ++ks) {
                kf = *(const bf16x8*)(sKn + ka[ks]);
                __builtin_amdgcn_s_setprio(1);
                sA0 = MFMA32(kf, qf[0][ks], sA0);
                sA1 = MFMA32(kf, qf[1][ks], sA1);
                __builtin_amdgcn_s_setprio(0);
            }
        }
        softmax_pv(sB0, sB1, 1, sVc);

        if (t < 15) {
            // drain prefetch (issued a full iteration before its first read)
            // and publish tile t+2; protects off2 overwrite (all waves done
            // reading tile t-1 at the previous barrier).
            asm volatile("s_waitcnt vmcnt(0) lgkmcnt(0)" ::: "memory");
            __builtin_amdgcn_s_barrier();
            __builtin_amdgcn_sched_barrier(0);
        }
        int tmp = off0; off0 = off1; off1 = off2; off2 = tmp;
    }

    // ---- kh-half merge epilogue ----
    // kh=1 waves park partials in LDS; kh=0 waves add and write O.
    __syncthreads();
    float* sf = (float*)sAll;            // 64 KB: oacc partials (4 qq x 64 ln x 64)
    float* sl = sf + 16384;              // 4 KB: l2 partials
    if (kh == 1) {
        const int base = (qq * 64 + lane) * 64;
#pragma unroll
        for (int qt = 0; qt < 2; ++qt)
#pragma unroll
            for (int dt = 0; dt < 2; ++dt) {
                int chunk = (qt * 2 + dt) ^ (lane & 3);   // bank de-phase
                *(f32x16*)(sf + base + chunk * 16) = oacc[qt][dt];
            }
        *(f32x2*)(sl + (qq * 64 + lane) * 4 + 0) = l2[0];
        *(f32x2*)(sl + (qq * 64 + lane) * 4 + 2) = l2[1];
    }
    __syncthreads();
    if (kh == 0) {
        const int base = (qq * 64 + lane) * 64;
#pragma unroll
        for (int qt = 0; qt < 2; ++qt)
#pragma unroll
            for (int dt = 0; dt < 2; ++dt) {
                int chunk = (qt * 2 + dt) ^ (lane & 3);
                f32x16 part = *(const f32x16*)(sf + base + chunk * 16);
#pragma unroll
                for (int e = 0; e < 16; ++e) oacc[qt][dt][e] += part[e];
            }
        l2[0] += *(const f32x2*)(sl + (qq * 64 + lane) * 4 + 0);
        l2[1] += *(const f32x2*)(sl + (qq * 64 + lane) * 4 + 2);

        const int b = bh >> 3, hh = bh & 7;
#pragma unroll
        for (int qt = 0; qt < 2; ++qt) {
            float l_run = l2[qt][0] + l2[qt][1];
            l_run += __shfl_xor(l_run, 32);
            float inv = 1.f / fmaxf(l_run, 1e-20f);
            unsigned short* obase = O + ((size_t)(b * 2048 + q0 + qt * 32 + l31)) * 512 + hh * 64;
#pragma unroll
            for (int dt = 0; dt < 2; ++dt)
#pragma unroll
                for (int g = 0; g < 4; ++g) {
                    int d = dt * 32 + 8 * g + 4 * h;
                    unsigned int w0 = pk2(oacc[qt][dt][4 * g + 0] * inv,
                                          oacc[qt][dt][4 * g + 1] * inv);
                    unsigned int w1 = pk2(oacc[qt][dt][4 * g + 2] * inv,
                                          oacc[qt][dt][4 * g + 3] * inv);
                    uint2 w = {w0, w1};
                    *(uint2*)(obase + d) = w;
                }
        }
    }
}

// ---------------------------------------------------------------------------
extern "C" void kernel_launch(void* const* d_in, const int* in_sizes, int n_in,
                              void* d_out, int out_size, void* d_ws, size_t ws_size,
                              hipStream_t stream)
{
    const float* x      = (const float*)d_in[0];  // [4,2048,512]
    const float* qkv_w  = (const float*)d_in[1];  // [1536,512]
    const float* qkv_b  = (const float*)d_in[2];  // [1536]
    const float* proj_w = (const float*)d_in[3];  // [512,512]
    const float* proj_b = (const float*)d_in[4];  // [512]

    const size_t PER = 4u * 8u * 2048u * 64u;     // 4,194,304 elems (8 MB bf16)
    unsigned short* q_ws  = (unsigned short*)d_ws;
    unsigned short* k_ws  = q_ws  + PER;
    unsigned short* vt_ws = k_ws  + PER;
    unsigned short* ao_ws = vt_ws + PER;
    unsigned short* wb2   = ao_ws + PER;          // proj_w bf16 (0.5 MB)

    // bf16 scratch inside d_out (16 MB; dead until final GEMM overwrites it)
    unsigned short* xb = (unsigned short*)d_out;          // 8 MB
    unsigned short* wb = xb + PER;                        // 1.5 MB

    // 0) bulk fp32->bf16 of x, qkv_w, proj_w (one launch)
    cvt_bf16<<<dim3(640), 256, 0, stream>>>(x, qkv_w, proj_w, xb, wb, wb2);
    // 1) QKV projection: M=8192, N=1536, K=512 (XCD-remapped)
    gemm_qkv<<<dim3(768), 256, 0, stream>>>(xb, wb, qkv_b, q_ws, k_ws, vt_ws, 512);
    // 2) Flash attention: 256 blocks x 512 threads, half-tile T15 pipeline
    attn_fused<<<dim3(256), 512, 0, stream>>>(q_ws, k_ws, vt_ws, ao_ws);
    // 3) Output projection: M=8192, N=512, K=512 (XCD-remapped)
    gemm_out<<<dim3(512), 256, 0, stream>>>(ao_ws, wb2, proj_b, (float*)d_out, 512, 512);
}

// Round 8
// 155.433 us; speedup vs baseline: 1.0006x; 1.0006x over previous
//
#include <hip/hip_runtime.h>
#include <stdint.h>

// ---------------------------------------------------------------------------
// Fused MHA block: qkv proj -> flash attention -> out proj.
// Inputs fp32, output fp32; bf16 MFMA compute, fp32 accum.
// B=4 N=2048 C=512 H=8 D=64 fixed.
// R25: attn_fused = anti-phase wave groups. MFMA blocks its wave (no
// within-wave MFMA/VALU overlap: R23/R24 null results + guide §8), so
// overlap must be CROSS-wave. (1) qq=wave&3, kh=wave>>2: each SIMD hosts
// one kh=0 + one kh=1 wave (old kh=wave&1 put same-parity waves on a
// SIMD). (2) kh=1 group is software-pipelined one subtile: carries
// pending S(t,mt1) + 4 reg-preloaded V-frags across the barrier and runs
// softmax(pending) on VALU exactly while kh=0 runs QK on the matrix pipe.
// Reg-carried V => no LDS hazard; single barrier per tile preserved.
// ---------------------------------------------------------------------------

typedef short bf16x8 __attribute__((ext_vector_type(8)));   // 8 bf16 = 4 VGPRs
typedef float f32x2  __attribute__((ext_vector_type(2)));
typedef float f32x4  __attribute__((ext_vector_type(4)));
typedef float f32x16 __attribute__((ext_vector_type(16)));
typedef unsigned int u32x4 __attribute__((ext_vector_type(4)));

__device__ __forceinline__ unsigned short f2bf(float f) {
    unsigned int u = __builtin_bit_cast(unsigned int, f);
    u += 0x7fffu + ((u >> 16) & 1u);
    return (unsigned short)(u >> 16);
}
__device__ __forceinline__ unsigned int pk2(float a, float b) {
    return (unsigned int)f2bf(a) | ((unsigned int)f2bf(b) << 16);
}
__device__ __forceinline__ float fexp2(float x) {
    return __builtin_amdgcn_exp2f(x);    // bare v_exp_f32
}
__device__ __forceinline__ bf16x8 ld8_f32(const float* __restrict__ p) {
    float4 f0 = *(const float4*)p;
    float4 f1 = *(const float4*)(p + 4);
    u32x4 u = {pk2(f0.x, f0.y), pk2(f0.z, f0.w), pk2(f1.x, f1.y), pk2(f1.z, f1.w)};
    return __builtin_bit_cast(bf16x8, u);
}
__device__ __forceinline__ void async16(const void* g, void* l) {
    __builtin_amdgcn_global_load_lds(
        (const __attribute__((address_space(1))) unsigned int*)g,
        (__attribute__((address_space(3))) unsigned int*)l,
        16, 0, 0);
}

#define MFMA16(a, b, c) __builtin_amdgcn_mfma_f32_16x16x32_bf16((a), (b), (c), 0, 0, 0)
#define MFMA32(a, b, c) __builtin_amdgcn_mfma_f32_32x32x16_bf16((a), (b), (c), 0, 0, 0)

// ---------------------------------------------------------------------------
// fp32 -> bf16 bulk convert: x, qkv_w, proj_w in one pass.
// ---------------------------------------------------------------------------
__global__ void cvt_bf16(const float* __restrict__ x,
                         const float* __restrict__ w,
                         const float* __restrict__ w2,
                         unsigned short* __restrict__ xb,
                         unsigned short* __restrict__ wb,
                         unsigned short* __restrict__ wb2)
{
    const int G = 524288 + 98304 + 32768;
    for (int idx = blockIdx.x * 256 + threadIdx.x; idx < G; idx += gridDim.x * 256) {
        if (idx < 524288)
            *(bf16x8*)(xb + (size_t)idx * 8) = ld8_f32(x + (size_t)idx * 8);
        else if (idx < 524288 + 98304) {
            int j = idx - 524288;
            *(bf16x8*)(wb + (size_t)j * 8) = ld8_f32(w + (size_t)j * 8);
        } else {
            int j = idx - 524288 - 98304;
            *(bf16x8*)(wb2 + (size_t)j * 8) = ld8_f32(w2 + (size_t)j * 8);
        }
    }
}

// ---------------------------------------------------------------------------
// QKV GEMM: 128x128 tile / 4 waves; BK=32; dual DMA staging; 4 blocks/CU.
// XCD remap: XCD k owns A-rows [8k,8k+8) x all 12 col-tiles.
// ---------------------------------------------------------------------------
__global__ __launch_bounds__(256, 4)
void gemm_qkv(const unsigned short* __restrict__ A,
              const unsigned short* __restrict__ B,
              const float* __restrict__ bias,
              unsigned short* __restrict__ out0,
              unsigned short* __restrict__ out1,
              unsigned short* __restrict__ out2,
              int K)
{
    __shared__ unsigned short sA[128 * 32];
    __shared__ unsigned short sB[128 * 32];

    const int tid  = threadIdx.x;
    const int wave = tid >> 6, lane = tid & 63;
    const int l = lane & 15, q16 = lane >> 4;
    const int wm = wave >> 1, wn = wave & 1;
    const int bid = blockIdx.x;                  // 0..767
    const int slot = bid >> 3;                   // 0..95
    const int m0 = ((bid & 7) * 8 + slot / 12) * 128;
    const int n0 = (slot % 12) * 128;

    f32x4 acc[4][4];
#pragma unroll
    for (int i = 0; i < 4; ++i)
#pragma unroll
        for (int j = 0; j < 4; ++j)
            acc[i][j] = (f32x4){0.f, 0.f, 0.f, 0.f};

    for (int k0 = 0; k0 < K; k0 += 32) {
#pragma unroll
        for (int call = 0; call < 2; ++call) {
            int L = call * 256 + tid;
            int r = L >> 2, c = L & 3;
            async16(A + (size_t)(m0 + r) * K + k0 + c * 8, sA + L * 8);
            async16(B + (size_t)(n0 + r) * K + k0 + c * 8, sB + L * 8);
        }
        __syncthreads();

        bf16x8 af[4], bfr[4];
#pragma unroll
        for (int i = 0; i < 4; ++i)
            af[i] = *(const bf16x8*)(sA + ((wm * 64 + i * 16 + l) * 4 + q16) * 8);
#pragma unroll
        for (int j = 0; j < 4; ++j)
            bfr[j] = *(const bf16x8*)(sB + ((wn * 64 + j * 16 + l) * 4 + q16) * 8);
#pragma unroll
        for (int i = 0; i < 4; ++i)
#pragma unroll
            for (int j = 0; j < 4; ++j)
                acc[i][j] = MFMA16(af[i], bfr[j], acc[i][j]);
        __syncthreads();
    }

    const float lscale = 0.18033688f;  // D^-0.5 * log2(e), folded into q
#pragma unroll
    for (int i = 0; i < 4; ++i) {
#pragma unroll
        for (int j = 0; j < 4; ++j) {
            int col = n0 + wn * 64 + j * 16 + l;
            float bv = bias[col];
#pragma unroll
            for (int r = 0; r < 4; ++r) {
                int row = m0 + wm * 64 + i * 16 + q16 * 4 + r;
                float val = acc[i][j][r] + bv;
                int which = col >> 9;            // 0:q 1:k 2:v
                int h = (col >> 6) & 7, d = col & 63;
                int b = row >> 11, n = row & 2047;
                if (which == 0)
                    out0[(size_t)(((b * 8 + h) * 2048) + n) * 64 + d] = f2bf(val * lscale);
                else if (which == 1)
                    out1[(size_t)(((b * 8 + h) * 2048) + n) * 64 + d] = f2bf(val);
                else {
                    // V^T with pi(n): swap bits 2<->3 of n (within 32-blocks)
                    int np = (n & ~12) | ((n & 8) >> 1) | ((n & 4) << 1);
                    out2[(size_t)(((b * 8 + h) * 64) + d) * 2048 + np] = f2bf(val);
                }
            }
        }
    }
}

// ---------------------------------------------------------------------------
// Output GEMM: 64x128 tile / 4 waves; BK=32; 4 blocks/CU. fp32 out + bias.
// XCD remap: XCD k owns rows [16k,16k+16) x 4 col-tiles.
// ---------------------------------------------------------------------------
__global__ __launch_bounds__(256, 4)
void gemm_out(const unsigned short* __restrict__ A,
              const unsigned short* __restrict__ B,
              const float* __restrict__ bias,
              float* __restrict__ outf,
              int K, int N)
{
    __shared__ unsigned short sA[64 * 32];
    __shared__ unsigned short sB[128 * 32];

    const int tid  = threadIdx.x;
    const int wave = tid >> 6, lane = tid & 63;
    const int l = lane & 15, q16 = lane >> 4;
    const int wm = wave >> 1, wn = wave & 1;
    const int bid = blockIdx.x;                  // 0..511
    const int slot = bid >> 3;                   // 0..63
    const int m0 = ((bid & 7) * 16 + (slot >> 2)) * 64;
    const int n0 = (slot & 3) * 128;

    f32x4 acc[2][4];
#pragma unroll
    for (int i = 0; i < 2; ++i)
#pragma unroll
        for (int j = 0; j < 4; ++j)
            acc[i][j] = (f32x4){0.f, 0.f, 0.f, 0.f};

    for (int k0 = 0; k0 < K; k0 += 32) {
        {
            int r = tid >> 2, c = tid & 3;       // A: 256 slots
            async16(A + (size_t)(m0 + r) * K + k0 + c * 8, sA + tid * 8);
        }
#pragma unroll
        for (int call = 0; call < 2; ++call) {   // B: 512 slots
            int L = call * 256 + tid;
            int r = L >> 2, c = L & 3;
            async16(B + (size_t)(n0 + r) * K + k0 + c * 8, sB + L * 8);
        }
        __syncthreads();

        bf16x8 af[2], bfr[4];
#pragma unroll
        for (int i = 0; i < 2; ++i)
            af[i] = *(const bf16x8*)(sA + ((wm * 32 + i * 16 + l) * 4 + q16) * 8);
#pragma unroll
        for (int j = 0; j < 4; ++j)
            bfr[j] = *(const bf16x8*)(sB + ((wn * 64 + j * 16 + l) * 4 + q16) * 8);
#pragma unroll
        for (int i = 0; i < 2; ++i)
#pragma unroll
            for (int j = 0; j < 4; ++j)
                acc[i][j] = MFMA16(af[i], bfr[j], acc[i][j]);
        __syncthreads();
    }

#pragma unroll
    for (int i = 0; i < 2; ++i) {
#pragma unroll
        for (int j = 0; j < 4; ++j) {
            int col = n0 + wn * 64 + j * 16 + l;
            float bv = bias[col];
#pragma unroll
            for (int r = 0; r < 4; ++r) {
                int row = m0 + wm * 32 + i * 16 + q16 * 4 + r;
                outf[(size_t)row * N + col] = acc[i][j][r] + bv;
            }
        }
    }
}

// ---------------------------------------------------------------------------
// Flash attention R25: 512 threads / 8 waves / 1 block per CU.
// qq = wave&3 (q-quarter), kh = wave>>2 (kv-half): each SIMD hosts one
// kh=0 and one kh=1 wave. kh=1 pipelined one subtile (pending S + reg V):
// after each barrier, kh=1 runs softmax(pending) on VALU while kh=0 runs
// QK on the matrix pipe -> sustained cross-wave pipe overlap (MFMA blocks
// its wave; within-wave overlap is impossible). Triple-buffered LDS,
// prefetch t+2 at top of iter, counted vmcnt(4) before the single
// per-tile barrier. kh-partials merged additively via LDS epilogue.
// ---------------------------------------------------------------------------
__global__ __launch_bounds__(512)
void attn_fused(const unsigned short* __restrict__ Q,
                const unsigned short* __restrict__ Km,
                const unsigned short* __restrict__ Vt,
                unsigned short* __restrict__ O)
{
    __shared__ unsigned short sAll[49152];       // 96 KB: K[3][8192] | V[3][8192]

    const int tid  = threadIdx.x;
    const int wave = tid >> 6, lane = tid & 63;
    const int l31 = lane & 31, h = lane >> 5;
    const int swz = l31 & 7;
    const int qq = wave & 3, kh = wave >> 2;     // qq 0..3, kh 0..1 (SIMD-mixed)
    const int bid = blockIdx.x;                  // 0..255
    const int slot = bid >> 3;                   // 0..31
    const int bh = (bid & 7) * 4 + (slot >> 3);  // 4 heads per XCD
    const int qc = slot & 7;                     // q-chunk of 256 rows
    const int q0 = qc * 256 + qq * 64;           // this wave: q0..q0+63

    const unsigned short* Kp = Km + (size_t)bh * 2048 * 64;
    const unsigned short* Vp = Vt + (size_t)bh * 64 * 2048;
    unsigned short* sKf = sAll;                  // 3 x 8192-elem K buffers
    unsigned short* sVf = sAll + 24576;          // 3 x 8192-elem V buffers

    // K fragment addrs: row = kh*64 + mt*32 + l31 (row&7 == swz),
    // chunk = (ks*2+h)^swz. mt*2048 added at use.
    int ka[4], va[2][2];
#pragma unroll
    for (int ks = 0; ks < 4; ++ks)
        ka[ks] = (kh * 64 + l31) * 64 + ((ks * 2 + h) ^ swz) * 8;
    // V^T fragment addrs: row = d = l31 (+dt*32 via +4096), kv chunk
    // (mt*4+ks2*2+h)^swz within kh's 64-col half (+kh*64 raw offset).
#pragma unroll
    for (int m1 = 0; m1 < 2; ++m1)
#pragma unroll
        for (int ks2 = 0; ks2 < 2; ++ks2)
            va[m1][ks2] = l31 * 128 + ((m1 * 4 + ks2 * 2 + h) ^ swz) * 8 + kh * 64;

    // staging: 1024 slots of 8 elems, 512 threads -> 2 K slots + 2 V slots
    int ksrc[2], vsrc[2], dsl[2];
#pragma unroll
    for (int c = 0; c < 2; ++c) {
        int s = c * 512 + tid;
        int rk = s >> 3;
        ksrc[c] = rk * 64 + ((s & 7) ^ (rk & 7)) * 8;
        int rv = s >> 4;
        vsrc[c] = rv * 2048 + ((s & 15) ^ (rv & 7)) * 8;
        dsl[c] = s * 8;
    }

    bf16x8 qf[2][4];
#pragma unroll
    for (int qt = 0; qt < 2; ++qt)
#pragma unroll
        for (int ks = 0; ks < 4; ++ks)
            qf[qt][ks] = *(const bf16x8*)(Q + (size_t)(bh * 2048 + q0 + qt * 32 + l31) * 64
                                          + ks * 16 + h * 8);

    f32x16 oacc[2][2];
#pragma unroll
    for (int qt = 0; qt < 2; ++qt)
#pragma unroll
        for (int dt = 0; dt < 2; ++dt)
#pragma unroll
            for (int e = 0; e < 16; ++e) oacc[qt][dt][e] = 0.f;
    f32x16 Zv;
#pragma unroll
    for (int e = 0; e < 16; ++e) Zv[e] = 0.f;
    f32x2 l2[2];
    l2[0] = (f32x2){0.f, 0.f};
    l2[1] = (f32x2){0.f, 0.f};

    f32x16 sA0, sA1, sB0, sB1;                   // S buffers (sB = kh1 pending)
    bf16x8 vfpA = __builtin_bit_cast(bf16x8, (u32x4){0u, 0u, 0u, 0u});
    bf16x8 vfpB = vfpA, vfpC = vfpA, vfpD = vfpA;  // kh1 pending V frags

    // QK of one 32-kv subtile (both qt) from K @ sKc+mtOff.
    auto qk = [&](const unsigned short* sKc, int mtOff, f32x16& d0, f32x16& d1) {
        bf16x8 kf = *(const bf16x8*)(sKc + ka[0] + mtOff);
        __builtin_amdgcn_s_setprio(1);
        d0 = MFMA32(kf, qf[0][0], Zv);
        d1 = MFMA32(kf, qf[1][0], Zv);
        __builtin_amdgcn_s_setprio(0);
#pragma unroll
        for (int ks = 1; ks < 4; ++ks) {
            kf = *(const bf16x8*)(sKc + ka[ks] + mtOff);
            __builtin_amdgcn_s_setprio(1);
            d0 = MFMA32(kf, qf[0][ks], d0);
            d1 = MFMA32(kf, qf[1][ks], d1);
            __builtin_amdgcn_s_setprio(0);
        }
    };

    // softmax of one subtile pair -> 4 packed bf16 P-fragments.
    auto softmax_pack = [&](const f32x16& s0, const f32x16& s1,
                            bf16x8& f00, bf16x8& f01,
                            bf16x8& f10, bf16x8& f11) {
        unsigned int pk0[4][2], pk1[4][2];
#pragma unroll
        for (int g = 0; g < 4; ++g) {
            float a0 = fexp2(s0[4 * g + 0]);
            float a1 = fexp2(s0[4 * g + 1]);
            float a2 = fexp2(s0[4 * g + 2]);
            float a3 = fexp2(s0[4 * g + 3]);
            l2[0] += (f32x2){a0, a1};
            l2[0] += (f32x2){a2, a3};
            pk0[g][0] = __builtin_amdgcn_perm(
                __builtin_bit_cast(unsigned int, a1),
                __builtin_bit_cast(unsigned int, a0), 0x07060302u);
            pk0[g][1] = __builtin_amdgcn_perm(
                __builtin_bit_cast(unsigned int, a3),
                __builtin_bit_cast(unsigned int, a2), 0x07060302u);
            float b0 = fexp2(s1[4 * g + 0]);
            float b1 = fexp2(s1[4 * g + 1]);
            float b2 = fexp2(s1[4 * g + 2]);
            float b3 = fexp2(s1[4 * g + 3]);
            l2[1] += (f32x2){b0, b1};
            l2[1] += (f32x2){b2, b3};
            pk1[g][0] = __builtin_amdgcn_perm(
                __builtin_bit_cast(unsigned int, b1),
                __builtin_bit_cast(unsigned int, b0), 0x07060302u);
            pk1[g][1] = __builtin_amdgcn_perm(
                __builtin_bit_cast(unsigned int, b3),
                __builtin_bit_cast(unsigned int, b2), 0x07060302u);
        }
        u32x4 bu;
        bu[0] = pk0[0][0]; bu[1] = pk0[0][1]; bu[2] = pk0[1][0]; bu[3] = pk0[1][1];
        f00 = __builtin_bit_cast(bf16x8, bu);
        bu[0] = pk0[2][0]; bu[1] = pk0[2][1]; bu[2] = pk0[3][0]; bu[3] = pk0[3][1];
        f01 = __builtin_bit_cast(bf16x8, bu);
        bu[0] = pk1[0][0]; bu[1] = pk1[0][1]; bu[2] = pk1[1][0]; bu[3] = pk1[1][1];
        f10 = __builtin_bit_cast(bf16x8, bu);
        bu[0] = pk1[2][0]; bu[1] = pk1[2][1]; bu[2] = pk1[3][0]; bu[3] = pk1[3][1];
        f11 = __builtin_bit_cast(bf16x8, bu);
    };

    // PV from LDS V (subtile mt).
    auto pv_lds = [&](bf16x8 f00, bf16x8 f01, bf16x8 f10, bf16x8 f11,
                      int mt, const unsigned short* sVc) {
        bf16x8 v00 = *(const bf16x8*)(sVc + va[mt][0]);
        bf16x8 v01 = *(const bf16x8*)(sVc + va[mt][0] + 4096);
        bf16x8 v10 = *(const bf16x8*)(sVc + va[mt][1]);
        bf16x8 v11 = *(const bf16x8*)(sVc + va[mt][1] + 4096);
        __builtin_amdgcn_s_setprio(1);
        oacc[0][0] = MFMA32(v00, f00, oacc[0][0]);
        oacc[1][0] = MFMA32(v00, f10, oacc[1][0]);
        oacc[0][1] = MFMA32(v01, f00, oacc[0][1]);
        oacc[1][1] = MFMA32(v01, f10, oacc[1][1]);
        oacc[0][0] = MFMA32(v10, f01, oacc[0][0]);
        oacc[1][0] = MFMA32(v10, f11, oacc[1][0]);
        oacc[0][1] = MFMA32(v11, f01, oacc[0][1]);
        oacc[1][1] = MFMA32(v11, f11, oacc[1][1]);
        __builtin_amdgcn_s_setprio(0);
    };

    // PV from reg-carried V frags (kh=1 pending subtile).
    auto pv_reg = [&](bf16x8 f00, bf16x8 f01, bf16x8 f10, bf16x8 f11) {
        __builtin_amdgcn_s_setprio(1);
        oacc[0][0] = MFMA32(vfpA, f00, oacc[0][0]);
        oacc[1][0] = MFMA32(vfpA, f10, oacc[1][0]);
        oacc[0][1] = MFMA32(vfpB, f00, oacc[0][1]);
        oacc[1][1] = MFMA32(vfpB, f10, oacc[1][1]);
        oacc[0][0] = MFMA32(vfpC, f01, oacc[0][0]);
        oacc[1][0] = MFMA32(vfpC, f11, oacc[1][0]);
        oacc[0][1] = MFMA32(vfpD, f01, oacc[0][1]);
        oacc[1][1] = MFMA32(vfpD, f11, oacc[1][1]);
        __builtin_amdgcn_s_setprio(0);
    };

    // prologue: stage tiles 0 and 1; wait tile 0; publish.
#pragma unroll
    for (int c = 0; c < 2; ++c) {
        async16(Kp + ksrc[c], (void*)(sKf + dsl[c]));
        async16(Vp + vsrc[c], (void*)(sVf + dsl[c]));
    }
#pragma unroll
    for (int c = 0; c < 2; ++c) {
        async16(Kp + (size_t)128 * 64 + ksrc[c], (void*)(sKf + 8192 + dsl[c]));
        async16(Vp + (size_t)128 + vsrc[c], (void*)(sVf + 8192 + dsl[c]));
    }
    asm volatile("s_waitcnt vmcnt(4)" ::: "memory");
    __builtin_amdgcn_s_barrier();
    __builtin_amdgcn_sched_barrier(0);

    int off0 = 0, off1 = 8192, off2 = 16384;     // cur, +1, +2 buffer offsets

    for (int t = 0; t < 16; ++t) {
        const unsigned short* sKc = sKf + off0;
        const unsigned short* sVc = sVf + off0;

        // prefetch tile t+2 (writes buf holding tile t-1, fully read by the
        // end-of-(t-1) barrier; kh=1's pending V is reg-carried, no LDS read)
        if (t < 14) {
            size_t kv = (size_t)(t + 2) * 128;
#pragma unroll
            for (int c = 0; c < 2; ++c) {
                async16(Kp + kv * 64 + ksrc[c], (void*)(sKf + off2 + dsl[c]));
                async16(Vp + kv + vsrc[c], (void*)(sVf + off2 + dsl[c]));
            }
        }

        // kh=1: finish pending subtile (t-1, mt1) -- VALU-first, anti-phased
        // against kh=0's QK below on the same SIMD.
        if (kh == 1 && t > 0) {
            bf16x8 f00, f01, f10, f11;
            softmax_pack(sB0, sB1, f00, f01, f10, f11);
            pv_reg(f00, f01, f10, f11);
        }

        // subtile mt0: QK -> softmax -> PV (all waves)
        qk(sKc, 0, sA0, sA1);
        {
            bf16x8 f00, f01, f10, f11;
            softmax_pack(sA0, sA1, f00, f01, f10, f11);
            pv_lds(f00, f01, f10, f11, 0, sVc);
        }

        // subtile mt1: kh=0 finishes it now; kh=1 leaves it pending and
        // preloads its V fragments into registers (valid across barrier).
        if (kh == 0) {
            qk(sKc, 2048, sB0, sB1);
            bf16x8 f00, f01, f10, f11;
            softmax_pack(sB0, sB1, f00, f01, f10, f11);
            pv_lds(f00, f01, f10, f11, 1, sVc);
        } else {
            qk(sKc, 2048, sB0, sB1);
            vfpA = *(const bf16x8*)(sVc + va[1][0]);
            vfpB = *(const bf16x8*)(sVc + va[1][0] + 4096);
            vfpC = *(const bf16x8*)(sVc + va[1][1]);
            vfpD = *(const bf16x8*)(sVc + va[1][1] + 4096);
        }

        // counted wait: pf(t+1)'s 4 loads are the oldest outstanding;
        // pf(t+2)'s 4 stay in flight.
        if (t < 14) {
            asm volatile("s_waitcnt vmcnt(4)" ::: "memory");
        } else if (t == 14) {
            asm volatile("s_waitcnt vmcnt(0)" ::: "memory");
        }
        if (t < 15) {
            asm volatile("s_waitcnt lgkmcnt(0)" ::: "memory");
            __builtin_amdgcn_s_barrier();
            __builtin_amdgcn_sched_barrier(0);
        }
        int tmp = off0; off0 = off1; off1 = off2; off2 = tmp;
    }

    // kh=1: final pending subtile (15, mt1) via reg V.
    if (kh == 1) {
        bf16x8 f00, f01, f10, f11;
        softmax_pack(sB0, sB1, f00, f01, f10, f11);
        pv_reg(f00, f01, f10, f11);
    }

    // ---- kh-half merge epilogue ----
    // kh=1 waves park partials in LDS; kh=0 waves add and write O.
    __syncthreads();
    float* sf = (float*)sAll;            // 64 KB: oacc partials (4 qq x 64 ln x 64)
    float* sl = sf + 16384;              // 4 KB: l2 partials
    if (kh == 1) {
        const int base = (qq * 64 + lane) * 64;
#pragma unroll
        for (int qt = 0; qt < 2; ++qt)
#pragma unroll
            for (int dt = 0; dt < 2; ++dt) {
                int chunk = (qt * 2 + dt) ^ (lane & 3);   // bank de-phase
                *(f32x16*)(sf + base + chunk * 16) = oacc[qt][dt];
            }
        *(f32x2*)(sl + (qq * 64 + lane) * 4 + 0) = l2[0];
        *(f32x2*)(sl + (qq * 64 + lane) * 4 + 2) = l2[1];
    }
    __syncthreads();
    if (kh == 0) {
        const int base = (qq * 64 + lane) * 64;
#pragma unroll
        for (int qt = 0; qt < 2; ++qt)
#pragma unroll
            for (int dt = 0; dt < 2; ++dt) {
                int chunk = (qt * 2 + dt) ^ (lane & 3);
                f32x16 part = *(const f32x16*)(sf + base + chunk * 16);
#pragma unroll
                for (int e = 0; e < 16; ++e) oacc[qt][dt][e] += part[e];
            }
        l2[0] += *(const f32x2*)(sl + (qq * 64 + lane) * 4 + 0);
        l2[1] += *(const f32x2*)(sl + (qq * 64 + lane) * 4 + 2);

        const int b = bh >> 3, hh = bh & 7;
#pragma unroll
        for (int qt = 0; qt < 2; ++qt) {
            float l_run = l2[qt][0] + l2[qt][1];
            l_run += __shfl_xor(l_run, 32);
            float inv = 1.f / fmaxf(l_run, 1e-20f);
            unsigned short* obase = O + ((size_t)(b * 2048 + q0 + qt * 32 + l31)) * 512 + hh * 64;
#pragma unroll
            for (int dt = 0; dt < 2; ++dt)
#pragma unroll
                for (int g = 0; g < 4; ++g) {
                    int d = dt * 32 + 8 * g + 4 * h;
                    unsigned int w0 = pk2(oacc[qt][dt][4 * g + 0] * inv,
                                          oacc[qt][dt][4 * g + 1] * inv);
                    unsigned int w1 = pk2(oacc[qt][dt][4 * g + 2] * inv,
                                          oacc[qt][dt][4 * g + 3] * inv);
                    uint2 w = {w0, w1};
                    *(uint2*)(obase + d) = w;
                }
        }
    }
}

// ---------------------------------------------------------------------------
extern "C" void kernel_launch(void* const* d_in, const int* in_sizes, int n_in,
                              void* d_out, int out_size, void* d_ws, size_t ws_size,
                              hipStream_t stream)
{
    const float* x      = (const float*)d_in[0];  // [4,2048,512]
    const float* qkv_w  = (const float*)d_in[1];  // [1536,512]
    const float* qkv_b  = (const float*)d_in[2];  // [1536]
    const float* proj_w = (const float*)d_in[3];  // [512,512]
    const float* proj_b = (const float*)d_in[4];  // [512]

    const size_t PER = 4u * 8u * 2048u * 64u;     // 4,194,304 elems (8 MB bf16)
    unsigned short* q_ws  = (unsigned short*)d_ws;
    unsigned short* k_ws  = q_ws  + PER;
    unsigned short* vt_ws = k_ws  + PER;
    unsigned short* ao_ws = vt_ws + PER;
    unsigned short* wb2   = ao_ws + PER;          // proj_w bf16 (0.5 MB)

    // bf16 scratch inside d_out (16 MB; dead until final GEMM overwrites it)
    unsigned short* xb = (unsigned short*)d_out;          // 8 MB
    unsigned short* wb = xb + PER;                        // 1.5 MB

    // 0) bulk fp32->bf16 of x, qkv_w, proj_w (one launch)
    cvt_bf16<<<dim3(640), 256, 0, stream>>>(x, qkv_w, proj_w, xb, wb, wb2);
    // 1) QKV projection: M=8192, N=1536, K=512 (XCD-remapped)
    gemm_qkv<<<dim3(768), 256, 0, stream>>>(xb, wb, qkv_b, q_ws, k_ws, vt_ws, 512);
    // 2) Flash attention: 256 blocks x 512 threads, anti-phase wave groups
    attn_fused<<<dim3(256), 512, 0, stream>>>(q_ws, k_ws, vt_ws, ao_ws);
    // 3) Output projection: M=8192, N=512, K=512 (XCD-remapped)
    gemm_out<<<dim3(512), 256, 0, stream>>>(ao_ws, wb2, proj_b, (float*)d_out, 512, 512);
}

// Round 10
// 150.637 us; speedup vs baseline: 1.0324x; 1.0318x over previous
//
#include <hip/hip_runtime.h>
#include <stdint.h>

// ---------------------------------------------------------------------------
// Fused MHA block: qkv proj -> flash attention -> out proj.
// Inputs fp32, output fp32; bf16 MFMA compute, fp32 accum.
// B=4 N=2048 C=512 H=8 D=64 fixed.
// R27: R26 (LDS-free attention) + one-line fix: merge-epilogue LDS was
// smrg[16384+512] but l2 partials index up to 16384+1023 -> OOB into the
// co-resident block's LDS -> corrupted softmax denominators (absmax 7e-2).
// Now smrg[16384+1024]. Everything else identical to R26:
// gemm_qkv writes K/V in MFMA-fragment order (frag = 64 lanes x 16B = 1KB
// contiguous); attn loads each fragment as one coalesced dwordx4 from L2
// (KV/head 512KB, 4 heads/XCD = 2MB L2-resident). No LDS staging, no
// barriers, no bank conflicts in the main loop; waves free-run.
// ---------------------------------------------------------------------------

typedef short bf16x8 __attribute__((ext_vector_type(8)));   // 8 bf16 = 4 VGPRs
typedef float f32x2  __attribute__((ext_vector_type(2)));
typedef float f32x4  __attribute__((ext_vector_type(4)));
typedef float f32x16 __attribute__((ext_vector_type(16)));
typedef unsigned int u32x4 __attribute__((ext_vector_type(4)));

__device__ __forceinline__ unsigned short f2bf(float f) {
    unsigned int u = __builtin_bit_cast(unsigned int, f);
    u += 0x7fffu + ((u >> 16) & 1u);
    return (unsigned short)(u >> 16);
}
__device__ __forceinline__ unsigned int pk2(float a, float b) {
    return (unsigned int)f2bf(a) | ((unsigned int)f2bf(b) << 16);
}
__device__ __forceinline__ float fexp2(float x) {
    return __builtin_amdgcn_exp2f(x);    // bare v_exp_f32
}
__device__ __forceinline__ bf16x8 ld8_f32(const float* __restrict__ p) {
    float4 f0 = *(const float4*)p;
    float4 f1 = *(const float4*)(p + 4);
    u32x4 u = {pk2(f0.x, f0.y), pk2(f0.z, f0.w), pk2(f1.x, f1.y), pk2(f1.z, f1.w)};
    return __builtin_bit_cast(bf16x8, u);
}
__device__ __forceinline__ void async16(const void* g, void* l) {
    __builtin_amdgcn_global_load_lds(
        (const __attribute__((address_space(1))) unsigned int*)g,
        (__attribute__((address_space(3))) unsigned int*)l,
        16, 0, 0);
}

#define MFMA16(a, b, c) __builtin_amdgcn_mfma_f32_16x16x32_bf16((a), (b), (c), 0, 0, 0)
#define MFMA32(a, b, c) __builtin_amdgcn_mfma_f32_32x32x16_bf16((a), (b), (c), 0, 0, 0)

// ---------------------------------------------------------------------------
// fp32 -> bf16 bulk convert: x, qkv_w, proj_w in one pass.
// ---------------------------------------------------------------------------
__global__ void cvt_bf16(const float* __restrict__ x,
                         const float* __restrict__ w,
                         const float* __restrict__ w2,
                         unsigned short* __restrict__ xb,
                         unsigned short* __restrict__ wb,
                         unsigned short* __restrict__ wb2)
{
    const int G = 524288 + 98304 + 32768;
    for (int idx = blockIdx.x * 256 + threadIdx.x; idx < G; idx += gridDim.x * 256) {
        if (idx < 524288)
            *(bf16x8*)(xb + (size_t)idx * 8) = ld8_f32(x + (size_t)idx * 8);
        else if (idx < 524288 + 98304) {
            int j = idx - 524288;
            *(bf16x8*)(wb + (size_t)j * 8) = ld8_f32(w + (size_t)j * 8);
        } else {
            int j = idx - 524288 - 98304;
            *(bf16x8*)(wb2 + (size_t)j * 8) = ld8_f32(w2 + (size_t)j * 8);
        }
    }
}

// ---------------------------------------------------------------------------
// QKV GEMM: 128x128 tile / 4 waves; BK=32; dual DMA staging; 4 blocks/CU.
// Epilogue writes Q rows, K frag-ordered, V frag-ordered (see attn).
// ---------------------------------------------------------------------------
__global__ __launch_bounds__(256, 4)
void gemm_qkv(const unsigned short* __restrict__ A,
              const unsigned short* __restrict__ B,
              const float* __restrict__ bias,
              unsigned short* __restrict__ out0,
              unsigned short* __restrict__ out1,
              unsigned short* __restrict__ out2,
              int K)
{
    __shared__ unsigned short sA[128 * 32];
    __shared__ unsigned short sB[128 * 32];

    const int tid  = threadIdx.x;
    const int wave = tid >> 6, lane = tid & 63;
    const int l = lane & 15, q16 = lane >> 4;
    const int wm = wave >> 1, wn = wave & 1;
    const int bid = blockIdx.x;                  // 0..767
    const int slot = bid >> 3;                   // 0..95
    const int m0 = ((bid & 7) * 8 + slot / 12) * 128;
    const int n0 = (slot % 12) * 128;

    f32x4 acc[4][4];
#pragma unroll
    for (int i = 0; i < 4; ++i)
#pragma unroll
        for (int j = 0; j < 4; ++j)
            acc[i][j] = (f32x4){0.f, 0.f, 0.f, 0.f};

    for (int k0 = 0; k0 < K; k0 += 32) {
#pragma unroll
        for (int call = 0; call < 2; ++call) {
            int L = call * 256 + tid;
            int r = L >> 2, c = L & 3;
            async16(A + (size_t)(m0 + r) * K + k0 + c * 8, sA + L * 8);
            async16(B + (size_t)(n0 + r) * K + k0 + c * 8, sB + L * 8);
        }
        __syncthreads();

        bf16x8 af[4], bfr[4];
#pragma unroll
        for (int i = 0; i < 4; ++i)
            af[i] = *(const bf16x8*)(sA + ((wm * 64 + i * 16 + l) * 4 + q16) * 8);
#pragma unroll
        for (int j = 0; j < 4; ++j)
            bfr[j] = *(const bf16x8*)(sB + ((wn * 64 + j * 16 + l) * 4 + q16) * 8);
#pragma unroll
        for (int i = 0; i < 4; ++i)
#pragma unroll
            for (int j = 0; j < 4; ++j)
                acc[i][j] = MFMA16(af[i], bfr[j], acc[i][j]);
        __syncthreads();
    }

    const float lscale = 0.18033688f;  // D^-0.5 * log2(e), folded into q
#pragma unroll
    for (int i = 0; i < 4; ++i) {
#pragma unroll
        for (int j = 0; j < 4; ++j) {
            int col = n0 + wn * 64 + j * 16 + l;
            float bv = bias[col];
#pragma unroll
            for (int r = 0; r < 4; ++r) {
                int row = m0 + wm * 64 + i * 16 + q16 * 4 + r;
                float val = acc[i][j][r] + bv;
                int which = col >> 9;            // 0:q 1:k 2:v
                int hd = (col >> 6) & 7, d = col & 63;
                int b = row >> 11, n = row & 2047;
                int bh = b * 8 + hd;
                if (which == 0) {
                    out0[(size_t)((bh * 2048) + n) * 64 + d] = f2bf(val * lscale);
                } else if (which == 1) {
                    // K frag order: content K[n][d] at
                    // frag(t,kh,mt,ks), lane = h2*32 + (n&31), elem = d&7
                    int t = n >> 7, kh2 = (n >> 6) & 1, mt = (n >> 5) & 1;
                    int l31o = n & 31;
                    int ks = (d >> 4) & 3, h2 = (d >> 3) & 1, e = d & 7;
                    size_t frag = ((((size_t)bh * 16 + t) * 2 + kh2) * 2 + mt) * 4 + ks;
                    out1[frag * 512 + (h2 * 32 + l31o) * 8 + e] = f2bf(val);
                } else {
                    // V frag order, derived from the pi-permuted V^T image:
                    // np = pi(n); frag(t,kh,m1,ks2,dt), lane = h2*32+(d&31)
                    int np = (n & ~12) | ((n & 8) >> 1) | ((n & 4) << 1);
                    int t = np >> 7, kh2 = (np >> 6) & 1;
                    int c = (np >> 3) & 7, e = np & 7;
                    int m1 = (c >> 2) & 1, ks2 = (c >> 1) & 1, h2 = c & 1;
                    int dt = d >> 5, l31o = d & 31;
                    size_t frag = (((((size_t)bh * 16 + t) * 2 + kh2) * 2 + m1) * 2
                                   + ks2) * 2 + dt;
                    out2[frag * 512 + (h2 * 32 + l31o) * 8 + e] = f2bf(val);
                }
            }
        }
    }
}

// ---------------------------------------------------------------------------
// Output GEMM: 64x128 tile / 4 waves; BK=32; 4 blocks/CU. fp32 out + bias.
// ---------------------------------------------------------------------------
__global__ __launch_bounds__(256, 4)
void gemm_out(const unsigned short* __restrict__ A,
              const unsigned short* __restrict__ B,
              const float* __restrict__ bias,
              float* __restrict__ outf,
              int K, int N)
{
    __shared__ unsigned short sA[64 * 32];
    __shared__ unsigned short sB[128 * 32];

    const int tid  = threadIdx.x;
    const int wave = tid >> 6, lane = tid & 63;
    const int l = lane & 15, q16 = lane >> 4;
    const int wm = wave >> 1, wn = wave & 1;
    const int bid = blockIdx.x;                  // 0..511
    const int slot = bid >> 3;                   // 0..63
    const int m0 = ((bid & 7) * 16 + (slot >> 2)) * 64;
    const int n0 = (slot & 3) * 128;

    f32x4 acc[2][4];
#pragma unroll
    for (int i = 0; i < 2; ++i)
#pragma unroll
        for (int j = 0; j < 4; ++j)
            acc[i][j] = (f32x4){0.f, 0.f, 0.f, 0.f};

    for (int k0 = 0; k0 < K; k0 += 32) {
        {
            int r = tid >> 2, c = tid & 3;       // A: 256 slots
            async16(A + (size_t)(m0 + r) * K + k0 + c * 8, sA + tid * 8);
        }
#pragma unroll
        for (int call = 0; call < 2; ++call) {   // B: 512 slots
            int L = call * 256 + tid;
            int r = L >> 2, c = L & 3;
            async16(B + (size_t)(n0 + r) * K + k0 + c * 8, sB + L * 8);
        }
        __syncthreads();

        bf16x8 af[2], bfr[4];
#pragma unroll
        for (int i = 0; i < 2; ++i)
            af[i] = *(const bf16x8*)(sA + ((wm * 32 + i * 16 + l) * 4 + q16) * 8);
#pragma unroll
        for (int j = 0; j < 4; ++j)
            bfr[j] = *(const bf16x8*)(sB + ((wn * 64 + j * 16 + l) * 4 + q16) * 8);
#pragma unroll
        for (int i = 0; i < 2; ++i)
#pragma unroll
            for (int j = 0; j < 4; ++j)
                acc[i][j] = MFMA16(af[i], bfr[j], acc[i][j]);
        __syncthreads();
    }

#pragma unroll
    for (int i = 0; i < 2; ++i) {
#pragma unroll
        for (int j = 0; j < 4; ++j) {
            int col = n0 + wn * 64 + j * 16 + l;
            float bv = bias[col];
#pragma unroll
            for (int r = 0; r < 4; ++r) {
                int row = m0 + wm * 32 + i * 16 + q16 * 4 + r;
                outf[(size_t)row * N + col] = acc[i][j][r] + bv;
            }
        }
    }
}

// ---------------------------------------------------------------------------
// Flash attention R27: LDS-free. 512 threads / 8 waves; wave (qq,kh) owns
// 64 q-rows (qt 0,1) x kv-half kh. Every MFMA fragment of K/V is one
// coalesced 1KB global load from L2 (frag-ordered by gemm_qkv). No
// barriers in the main loop; K reg-double-buffered one subtile ahead;
// V issued at subtile start, consumed after softmax.
// kh-partials merged additively via small LDS epilogue (68KB, in-bounds).
// ---------------------------------------------------------------------------
__global__ __launch_bounds__(512)
void attn_fused(const unsigned short* __restrict__ Q,
                const unsigned short* __restrict__ Kfr,
                const unsigned short* __restrict__ Vfr,
                unsigned short* __restrict__ O)
{
    __shared__ float smrg[16384 + 1024];         // oacc partials + l2 partials

    const int tid  = threadIdx.x;
    const int wave = tid >> 6, lane = tid & 63;
    const int l31 = lane & 31, h = lane >> 5;
    const int qq = wave & 3, kh = wave >> 2;     // each SIMD mixes kh 0/1
    const int bid = blockIdx.x;                  // 0..255
    const int slot = bid >> 3;                   // 0..31
    const int bh = (bid & 7) * 4 + (slot >> 3);  // 4 heads per XCD
    const int qc = slot & 7;                     // q-chunk of 256 rows
    const int q0 = qc * 256 + qq * 64;           // this wave: q0..q0+63

    // Fragment bases (element units). Per head: 131072 elems (256KB).
    // K frag: + t*8192 + mt*2048 + ks*512 ; V frag: + t*8192 + m1*2048
    //         + ks2*1024 + dt*512. kh stride 4096 in both.
    const unsigned short* Kb = Kfr + (size_t)bh * 131072 + kh * 4096 + lane * 8;
    const unsigned short* Vb = Vfr + (size_t)bh * 131072 + kh * 4096 + lane * 8;

    bf16x8 qf[2][4];
#pragma unroll
    for (int qt = 0; qt < 2; ++qt)
#pragma unroll
        for (int ks = 0; ks < 4; ++ks)
            qf[qt][ks] = *(const bf16x8*)(Q + (size_t)(bh * 2048 + q0 + qt * 32 + l31) * 64
                                          + ks * 16 + h * 8);

    f32x16 oacc[2][2];
#pragma unroll
    for (int qt = 0; qt < 2; ++qt)
#pragma unroll
        for (int dt = 0; dt < 2; ++dt)
#pragma unroll
            for (int e = 0; e < 16; ++e) oacc[qt][dt][e] = 0.f;
    f32x16 Zv;
#pragma unroll
    for (int e = 0; e < 16; ++e) Zv[e] = 0.f;
    f32x2 l2[2];
    l2[0] = (f32x2){0.f, 0.f};
    l2[1] = (f32x2){0.f, 0.f};

    // softmax of one subtile pair -> 4 packed bf16 P-fragments.
    auto softmax_pack = [&](const f32x16& s0, const f32x16& s1,
                            bf16x8& f00, bf16x8& f01,
                            bf16x8& f10, bf16x8& f11) {
        unsigned int pk0[4][2], pk1[4][2];
#pragma unroll
        for (int g = 0; g < 4; ++g) {
            float a0 = fexp2(s0[4 * g + 0]);
            float a1 = fexp2(s0[4 * g + 1]);
            float a2 = fexp2(s0[4 * g + 2]);
            float a3 = fexp2(s0[4 * g + 3]);
            l2[0] += (f32x2){a0, a1};
            l2[0] += (f32x2){a2, a3};
            pk0[g][0] = __builtin_amdgcn_perm(
                __builtin_bit_cast(unsigned int, a1),
                __builtin_bit_cast(unsigned int, a0), 0x07060302u);
            pk0[g][1] = __builtin_amdgcn_perm(
                __builtin_bit_cast(unsigned int, a3),
                __builtin_bit_cast(unsigned int, a2), 0x07060302u);
            float b0 = fexp2(s1[4 * g + 0]);
            float b1 = fexp2(s1[4 * g + 1]);
            float b2 = fexp2(s1[4 * g + 2]);
            float b3 = fexp2(s1[4 * g + 3]);
            l2[1] += (f32x2){b0, b1};
            l2[1] += (f32x2){b2, b3};
            pk1[g][0] = __builtin_amdgcn_perm(
                __builtin_bit_cast(unsigned int, b1),
                __builtin_bit_cast(unsigned int, b0), 0x07060302u);
            pk1[g][1] = __builtin_amdgcn_perm(
                __builtin_bit_cast(unsigned int, b3),
                __builtin_bit_cast(unsigned int, b2), 0x07060302u);
        }
        u32x4 bu;
        bu[0] = pk0[0][0]; bu[1] = pk0[0][1]; bu[2] = pk0[1][0]; bu[3] = pk0[1][1];
        f00 = __builtin_bit_cast(bf16x8, bu);
        bu[0] = pk0[2][0]; bu[1] = pk0[2][1]; bu[2] = pk0[3][0]; bu[3] = pk0[3][1];
        f01 = __builtin_bit_cast(bf16x8, bu);
        bu[0] = pk1[0][0]; bu[1] = pk1[0][1]; bu[2] = pk1[1][0]; bu[3] = pk1[1][1];
        f10 = __builtin_bit_cast(bf16x8, bu);
        bu[0] = pk1[2][0]; bu[1] = pk1[2][1]; bu[2] = pk1[3][0]; bu[3] = pk1[3][1];
        f11 = __builtin_bit_cast(bf16x8, bu);
    };

    bf16x8 kA[4], kB[4], vv[2][2];

    // prologue: K frags of subtile (t=0, mt=0)
#pragma unroll
    for (int ks = 0; ks < 4; ++ks)
        kA[ks] = *(const bf16x8*)(Kb + ks * 512);

    for (int t = 0; t < 16; ++t) {
        const size_t tb = (size_t)t * 8192;

        // ---- subtile (t, mt=0): V issue, K(t,1) issue, QK(kA), SM, PV ----
#pragma unroll
        for (int ks2 = 0; ks2 < 2; ++ks2)
#pragma unroll
            for (int dt = 0; dt < 2; ++dt)
                vv[ks2][dt] = *(const bf16x8*)(Vb + tb + ks2 * 1024 + dt * 512);
#pragma unroll
        for (int ks = 0; ks < 4; ++ks)
            kB[ks] = *(const bf16x8*)(Kb + tb + 2048 + ks * 512);

        f32x16 s0, s1;
        __builtin_amdgcn_s_setprio(1);
        s0 = MFMA32(kA[0], qf[0][0], Zv);
        s1 = MFMA32(kA[0], qf[1][0], Zv);
#pragma unroll
        for (int ks = 1; ks < 4; ++ks) {
            s0 = MFMA32(kA[ks], qf[0][ks], s0);
            s1 = MFMA32(kA[ks], qf[1][ks], s1);
        }
        __builtin_amdgcn_s_setprio(0);
        {
            bf16x8 f00, f01, f10, f11;
            softmax_pack(s0, s1, f00, f01, f10, f11);
            __builtin_amdgcn_s_setprio(1);
            oacc[0][0] = MFMA32(vv[0][0], f00, oacc[0][0]);
            oacc[1][0] = MFMA32(vv[0][0], f10, oacc[1][0]);
            oacc[0][1] = MFMA32(vv[0][1], f00, oacc[0][1]);
            oacc[1][1] = MFMA32(vv[0][1], f10, oacc[1][1]);
            oacc[0][0] = MFMA32(vv[1][0], f01, oacc[0][0]);
            oacc[1][0] = MFMA32(vv[1][0], f11, oacc[1][0]);
            oacc[0][1] = MFMA32(vv[1][1], f01, oacc[0][1]);
            oacc[1][1] = MFMA32(vv[1][1], f11, oacc[1][1]);
            __builtin_amdgcn_s_setprio(0);
        }

        // ---- subtile (t, mt=1): V issue, K(t+1,0) issue, QK(kB), SM, PV ----
#pragma unroll
        for (int ks2 = 0; ks2 < 2; ++ks2)
#pragma unroll
            for (int dt = 0; dt < 2; ++dt)
                vv[ks2][dt] = *(const bf16x8*)(Vb + tb + 2048 + ks2 * 1024 + dt * 512);
        if (t < 15) {
#pragma unroll
            for (int ks = 0; ks < 4; ++ks)
                kA[ks] = *(const bf16x8*)(Kb + tb + 8192 + ks * 512);
        }

        __builtin_amdgcn_s_setprio(1);
        s0 = MFMA32(kB[0], qf[0][0], Zv);
        s1 = MFMA32(kB[0], qf[1][0], Zv);
#pragma unroll
        for (int ks = 1; ks < 4; ++ks) {
            s0 = MFMA32(kB[ks], qf[0][ks], s0);
            s1 = MFMA32(kB[ks], qf[1][ks], s1);
        }
        __builtin_amdgcn_s_setprio(0);
        {
            bf16x8 f00, f01, f10, f11;
            softmax_pack(s0, s1, f00, f01, f10, f11);
            __builtin_amdgcn_s_setprio(1);
            oacc[0][0] = MFMA32(vv[0][0], f00, oacc[0][0]);
            oacc[1][0] = MFMA32(vv[0][0], f10, oacc[1][0]);
            oacc[0][1] = MFMA32(vv[0][1], f00, oacc[0][1]);
            oacc[1][1] = MFMA32(vv[0][1], f10, oacc[1][1]);
            oacc[0][0] = MFMA32(vv[1][0], f01, oacc[0][0]);
            oacc[1][0] = MFMA32(vv[1][0], f11, oacc[1][0]);
            oacc[0][1] = MFMA32(vv[1][1], f01, oacc[0][1]);
            oacc[1][1] = MFMA32(vv[1][1], f11, oacc[1][1]);
            __builtin_amdgcn_s_setprio(0);
        }
    }

    // ---- kh-half merge epilogue (only sync in the kernel) ----
    __syncthreads();
    float* sf = smrg;                    // 64 KB: oacc partials
    float* sl = smrg + 16384;            // 4 KB: l2 partials (1024 floats)
    if (kh == 1) {
        const int base = (qq * 64 + lane) * 64;
#pragma unroll
        for (int qt = 0; qt < 2; ++qt)
#pragma unroll
            for (int dt = 0; dt < 2; ++dt) {
                int chunk = (qt * 2 + dt) ^ (lane & 3);   // bank de-phase
                *(f32x16*)(sf + base + chunk * 16) = oacc[qt][dt];
            }
        *(f32x2*)(sl + (qq * 64 + lane) * 4 + 0) = l2[0];
        *(f32x2*)(sl + (qq * 64 + lane) * 4 + 2) = l2[1];
    }
    __syncthreads();
    if (kh == 0) {
        const int base = (qq * 64 + lane) * 64;
#pragma unroll
        for (int qt = 0; qt < 2; ++qt)
#pragma unroll
            for (int dt = 0; dt < 2; ++dt) {
                int chunk = (qt * 2 + dt) ^ (lane & 3);
                f32x16 part = *(const f32x16*)(sf + base + chunk * 16);
#pragma unroll
                for (int e = 0; e < 16; ++e) oacc[qt][dt][e] += part[e];
            }
        l2[0] += *(const f32x2*)(sl + (qq * 64 + lane) * 4 + 0);
        l2[1] += *(const f32x2*)(sl + (qq * 64 + lane) * 4 + 2);

        const int b = bh >> 3, hh = bh & 7;
#pragma unroll
        for (int qt = 0; qt < 2; ++qt) {
            float l_run = l2[qt][0] + l2[qt][1];
            l_run += __shfl_xor(l_run, 32);
            float inv = 1.f / fmaxf(l_run, 1e-20f);
            unsigned short* obase = O + ((size_t)(b * 2048 + q0 + qt * 32 + l31)) * 512 + hh * 64;
#pragma unroll
            for (int dt = 0; dt < 2; ++dt)
#pragma unroll
                for (int g = 0; g < 4; ++g) {
                    int d = dt * 32 + 8 * g + 4 * h;
                    unsigned int w0 = pk2(oacc[qt][dt][4 * g + 0] * inv,
                                          oacc[qt][dt][4 * g + 1] * inv);
                    unsigned int w1 = pk2(oacc[qt][dt][4 * g + 2] * inv,
                                          oacc[qt][dt][4 * g + 3] * inv);
                    uint2 w = {w0, w1};
                    *(uint2*)(obase + d) = w;
                }
        }
    }
}

// ---------------------------------------------------------------------------
extern "C" void kernel_launch(void* const* d_in, const int* in_sizes, int n_in,
                              void* d_out, int out_size, void* d_ws, size_t ws_size,
                              hipStream_t stream)
{
    const float* x      = (const float*)d_in[0];  // [4,2048,512]
    const float* qkv_w  = (const float*)d_in[1];  // [1536,512]
    const float* qkv_b  = (const float*)d_in[2];  // [1536]
    const float* proj_w = (const float*)d_in[3];  // [512,512]
    const float* proj_b = (const float*)d_in[4];  // [512]

    const size_t PER = 4u * 8u * 2048u * 64u;     // 4,194,304 elems (8 MB bf16)
    unsigned short* q_ws  = (unsigned short*)d_ws;
    unsigned short* k_ws  = q_ws  + PER;          // K frag-ordered
    unsigned short* vt_ws = k_ws  + PER;          // V frag-ordered
    unsigned short* ao_ws = vt_ws + PER;
    unsigned short* wb2   = ao_ws + PER;          // proj_w bf16 (0.5 MB)

    // bf16 scratch inside d_out (16 MB; dead until final GEMM overwrites it)
    unsigned short* xb = (unsigned short*)d_out;          // 8 MB
    unsigned short* wb = xb + PER;                        // 1.5 MB

    // 0) bulk fp32->bf16 of x, qkv_w, proj_w (one launch)
    cvt_bf16<<<dim3(640), 256, 0, stream>>>(x, qkv_w, proj_w, xb, wb, wb2);
    // 1) QKV projection: M=8192, N=1536, K=512 (frag-ordered K/V epilogue)
    gemm_qkv<<<dim3(768), 256, 0, stream>>>(xb, wb, qkv_b, q_ws, k_ws, vt_ws, 512);
    // 2) Flash attention: 256 blocks x 512 threads, LDS-free L2 streaming
    attn_fused<<<dim3(256), 512, 0, stream>>>(q_ws, k_ws, vt_ws, ao_ws);
    // 3) Output projection: M=8192, N=512, K=512 (XCD-remapped)
    gemm_out<<<dim3(512), 256, 0, stream>>>(ao_ws, wb2, proj_b, (float*)d_out, 512, 512);
}